// Round 6
// baseline (193.794 us; speedup 1.0000x reference)
//
#include <hip/hip_runtime.h>
#include <math.h>

#define BB 32
#define SS 128
#define DIN 16
#define HH 128
#define NROW (BB*SS)      // 4096
#define NBSH (BB*SS*HH)   // 524288

__device__ __forceinline__ float4 f4add(float4 a, float4 b){
    return make_float4(a.x+b.x, a.y+b.y, a.z+b.z, a.w+b.w);
}

// ============ K0a: coalesced-read transposes ==================================
__global__ __launch_bounds__(256) void k_prep_t(
    const float* __restrict__ w12, const float* __restrict__ w22,
    const float* __restrict__ w31,
    float* __restrict__ w12T, float* __restrict__ w22T, float* __restrict__ W31T)
{
    int idx4 = blockIdx.x*256 + threadIdx.x;   // 130*256 = 33280 exactly
    if (idx4 < 12288){
        float4 v = reinterpret_cast<const float4*>(w12)[idx4];
        int e = idx4*4;
        const float* pv = (const float*)&v;
        #pragma unroll
        for (int u = 0; u < 4; ++u){
            int h = (e+u)/384, r = (e+u)%384;
            w12T[r*HH + h] = pv[u];
        }
    } else if (idx4 < 32768){
        int q = idx4 - 12288;
        float4 v = reinterpret_cast<const float4*>(w22)[q];
        int e = q*4;
        const float* pv = (const float*)&v;
        #pragma unroll
        for (int u = 0; u < 4; ++u){
            int h = (e+u)/640, r = (e+u)%640;
            w22T[r*HH + h] = pv[u];
        }
    } else if (idx4 < 33280){
        int q = idx4 - 32768;
        float4 v = reinterpret_cast<const float4*>(w31)[q];
        int e = q*4;
        const float* pv = (const float*)&v;
        #pragma unroll
        for (int u = 0; u < 4; ++u){
            int h = (e+u)/DIN, d = (e+u)%DIN;
            W31T[d*HH + h] = pv[u];
        }
    }
}

// ============ K0b: composite conv weights (coalesced in h) ====================
__global__ __launch_bounds__(128) void k_prep_w(
    const float* __restrict__ w12T, const float* __restrict__ w22T,
    const float* __restrict__ w11, const float* __restrict__ b11,
    const float* __restrict__ w21, const float* __restrict__ b21,
    float* __restrict__ W3, float* __restrict__ W5,
    float* __restrict__ Beff1, float* __restrict__ Beff2)
{
    int blk = blockIdx.x; int h = threadIdx.x;
    if (blk < 48){
        int k = blk >> 4, d = blk & 15;
        float acc = 0.f;
        #pragma unroll 4
        for (int c = 0; c < HH; ++c)
            acc = fmaf(w12T[(c*3+k)*HH + h], w11[c*DIN + d], acc);
        W3[(k*DIN+d)*HH + h] = acc;
    } else if (blk < 128){
        int kk = blk - 48; int k = kk >> 4, d = kk & 15;
        float acc = 0.f;
        #pragma unroll 4
        for (int c = 0; c < HH; ++c)
            acc = fmaf(w22T[(c*5+k)*HH + h], w21[c*DIN + d], acc);
        W5[(k*DIN+d)*HH + h] = acc;
    } else {
        int j = blk - 128;   // 0..7
        if (j < 3){
            float a = 0.f;
            #pragma unroll 4
            for (int c = 0; c < HH; ++c) a = fmaf(w12T[(c*3+j)*HH + h], b11[c], a);
            Beff1[j*HH + h] = a;
        } else {
            int k = j - 3;
            float a = 0.f;
            #pragma unroll 4
            for (int c = 0; c < HH; ++c) a = fmaf(w22T[(c*5+k)*HH + h], b21[c], a);
            Beff2[k*HH + h] = a;
        }
    }
}

// ============ K1: conv front end -> xcatT[c][row] (transposed) ================
__global__ __launch_bounds__(256) void k_conv_t(
    const float* __restrict__ data,
    const float* __restrict__ W3, const float* __restrict__ W5,
    const float* __restrict__ W31T,
    const float* __restrict__ Beff1, const float* __restrict__ Beff2,
    const float* __restrict__ b12, const float* __restrict__ b22,
    const float* __restrict__ b31,
    float* __restrict__ xcatT)
{
    int blk = blockIdx.x; int b = blk >> 4; int s0 = (blk & 15) * 8;
    int t = threadIdx.x; int h = t & 127; int g = t >> 7; int tg = 4*g;
    __shared__ __align__(16) float dinT[DIN*28];   // [d][r], sp = s0-10+r

    for (int idx = t; idx < 28*DIN; idx += 256){
        int r = idx >> 4, d = idx & 15;
        int sp = s0 - 10 + r;
        dinT[d*28 + r] = (sp >= 0 && sp < SS) ? data[(b*SS+sp)*DIN + d] : 0.f;
    }
    __syncthreads();

    float acc1[4] = {0,0,0,0}, acc2[4] = {0,0,0,0}, acc3[4] = {0,0,0,0};
    for (int d = 0; d < DIN; ++d){
        const float4* qp = reinterpret_cast<const float4*>(dinT + d*28 + tg);
        float4 q0=qp[0], q1=qp[1], q2=qp[2], q3=qp[3], q4=qp[4], q5=qp[5];
        float qf[24] = {q0.x,q0.y,q0.z,q0.w, q1.x,q1.y,q1.z,q1.w,
                        q2.x,q2.y,q2.z,q2.w, q3.x,q3.y,q3.z,q3.w,
                        q4.x,q4.y,q4.z,q4.w, q5.x,q5.y,q5.z,q5.w};
        #pragma unroll
        for (int k = 0; k < 3; ++k){
            float w = W3[(k*DIN+d)*HH + h];
            #pragma unroll
            for (int tp = 0; tp < 4; ++tp)
                acc1[tp] = fmaf(qf[tp + 3*k + 7], w, acc1[tp]);
        }
        #pragma unroll
        for (int k = 0; k < 5; ++k){
            float w = W5[(k*DIN+d)*HH + h];
            #pragma unroll
            for (int tp = 0; tp < 4; ++tp)
                acc2[tp] = fmaf(qf[tp + 5*k], w, acc2[tp]);
        }
        float w31v = W31T[d*HH + h];
        #pragma unroll
        for (int tp = 0; tp < 4; ++tp)
            acc3[tp] = fmaf(qf[tp + 10], w31v, acc3[tp]);
    }
    float be1[3] = {Beff1[h], Beff1[HH+h], Beff1[2*HH+h]};
    float be2[5] = {Beff2[h], Beff2[HH+h], Beff2[2*HH+h], Beff2[3*HH+h], Beff2[4*HH+h]};
    float bv12 = b12[h], bv22 = b22[h], bv31 = b31[h];
    float o1[4], o2[4], o3[4];
    #pragma unroll
    for (int tp = 0; tp < 4; ++tp){
        int s = s0 + tg + tp;
        float a1 = acc1[tp] + bv12;
        #pragma unroll
        for (int k = 0; k < 3; ++k)
            if ((unsigned)(s + 3*k - 3) < SS) a1 += be1[k];
        float a2 = acc2[tp] + bv22;
        #pragma unroll
        for (int k = 0; k < 5; ++k)
            if ((unsigned)(s + 5*k - 10) < SS) a2 += be2[k];
        o1[tp] = a1; o2[tp] = a2; o3[tp] = acc3[tp] + bv31;
    }
    size_t rbase = (size_t)(b*SS + s0 + tg);
    *reinterpret_cast<float4*>(xcatT + (size_t)h*NROW + rbase)          = make_float4(o1[0],o1[1],o1[2],o1[3]);
    *reinterpret_cast<float4*>(xcatT + (size_t)(HH+h)*NROW + rbase)     = make_float4(o2[0],o2[1],o2[2],o2[3]);
    *reinterpret_cast<float4*>(xcatT + (size_t)(2*HH+h)*NROW + rbase)   = make_float4(o3[0],o3[1],o3[2],o3[3]);
}

// ============ K2: fuse GEMM (uniform global acts, no LDS) + hs/hr =============
__global__ __launch_bounds__(256) void k_fuse_hs(
    const float* __restrict__ xcatT,
    const float* __restrict__ wf, const float* __restrict__ bf,
    const float* __restrict__ w1, const float* __restrict__ b1,
    float* __restrict__ x, float* __restrict__ hsT, float* __restrict__ hr)
{
    int blk = blockIdx.x; int b = blk >> 4; int s0 = (blk & 15) * 8;
    int t = threadIdx.x; int h = t & 127; int g = t >> 7; int tg = 4*g;
    __shared__ float4 xL[2][HH];
    size_t rbase = (size_t)(b*SS + s0 + tg);   // wave-uniform

    float bfv = bf[h];
    float fa[4] = {bfv,bfv,bfv,bfv};
    #pragma unroll 4
    for (int c = 0; c < 384; ++c){
        float4 a = *reinterpret_cast<const float4*>(xcatT + (size_t)c*NROW + rbase);
        float w = wf[c*HH + h];
        fa[0]=fmaf(a.x,w,fa[0]); fa[1]=fmaf(a.y,w,fa[1]);
        fa[2]=fmaf(a.z,w,fa[2]); fa[3]=fmaf(a.w,w,fa[3]);
    }
    float4 xv = make_float4(fmaxf(fa[0],0.f), fmaxf(fa[1],0.f),
                            fmaxf(fa[2],0.f), fmaxf(fa[3],0.f));
    size_t base = (size_t)(b*SS + s0 + tg)*HH + h;
    x[base] = xv.x; x[base+HH] = xv.y; x[base+2*HH] = xv.z; x[base+3*HH] = xv.w;
    xL[g][h] = xv;
    __syncthreads();

    float as[4]={0,0,0,0}, ar[4]={0,0,0,0};
    for (int c = 0; c < HH; ++c){
        float4 a = xL[g][c];
        float wsv = w1[c*HH+h], wrv = w1[(HH+c)*HH+h];
        as[0]=fmaf(a.x,wsv,as[0]); as[1]=fmaf(a.y,wsv,as[1]);
        as[2]=fmaf(a.z,wsv,as[2]); as[3]=fmaf(a.w,wsv,as[3]);
        ar[0]=fmaf(a.x,wrv,ar[0]); ar[1]=fmaf(a.y,wrv,ar[1]);
        ar[2]=fmaf(a.z,wrv,ar[2]); ar[3]=fmaf(a.w,wrv,ar[3]);
    }
    float b1v = b1[h];
    *reinterpret_cast<float4*>(hsT + ((size_t)b*HH + h)*SS + s0 + tg) =
        make_float4(as[0], as[1], as[2], as[3]);
    hr[base]      = ar[0] + b1v;
    hr[base+HH]   = ar[1] + b1v;
    hr[base+2*HH] = ar[2] + b1v;
    hr[base+3*HH] = ar[3] + b1v;
}

// ============ K3: edge logits + gumbel argmax -> adj (8-i tile) ===============
__global__ __launch_bounds__(256) void k_adj(
    const float* __restrict__ hsT, const float* __restrict__ hr,
    const float* __restrict__ w2, const float* __restrict__ b2,
    const float* __restrict__ gu, float* __restrict__ adj)
{
    int blk = blockIdx.x; int b = blk >> 4; int i0 = (blk & 15) * 8;
    int t = threadIdx.x; int j = t & 127; int g = t >> 7; int ig = i0 + 4*g;
    __shared__ float4 hrT[2][HH];
    __shared__ float w20L[HH], w21L[HH];
    hrT[g][j] = make_float4(hr[(size_t)(b*SS+ig+0)*HH + j],
                            hr[(size_t)(b*SS+ig+1)*HH + j],
                            hr[(size_t)(b*SS+ig+2)*HH + j],
                            hr[(size_t)(b*SS+ig+3)*HH + j]);
    if (g == 0){ w20L[j] = w2[j*2]; w21L[j] = w2[j*2+1]; }
    __syncthreads();
    const float* hsb = hsT + (size_t)b*HH*SS;
    float d0[4] = {0,0,0,0}, d1[4] = {0,0,0,0};
    #pragma unroll 2
    for (int h = 0; h < HH; ++h){
        float hsv = hsb[h*SS + j];
        float4 hv = hrT[g][h];
        float wa = w20L[h], wb = w21L[h];
        float r0 = fmaxf(hsv + hv.x, 0.f);
        float r1 = fmaxf(hsv + hv.y, 0.f);
        float r2 = fmaxf(hsv + hv.z, 0.f);
        float r3 = fmaxf(hsv + hv.w, 0.f);
        d0[0]=fmaf(r0,wa,d0[0]); d1[0]=fmaf(r0,wb,d1[0]);
        d0[1]=fmaf(r1,wa,d0[1]); d1[1]=fmaf(r1,wb,d1[1]);
        d0[2]=fmaf(r2,wa,d0[2]); d1[2]=fmaf(r2,wb,d1[2]);
        d0[3]=fmaf(r3,wa,d0[3]); d1[3]=fmaf(r3,wb,d1[3]);
    }
    float b20 = b2[0], b21 = b2[1];
    #pragma unroll
    for (int ii = 0; ii < 4; ++ii){
        int i = ig + ii;
        size_t e = (size_t)(b*SS+i)*SS + j;
        float2 uv = *reinterpret_cast<const float2*>(gu + e*2);
        float u0 = fminf(fmaxf(uv.x, 1e-6f), 0.999999f);
        float u1 = fminf(fmaxf(uv.y, 1e-6f), 0.999999f);
        float g0 = -logf(-logf(u0));
        float g1 = -logf(-logf(u1));
        float y0 = d0[ii] + b20 + g0;
        float y1 = d1[ii] + b21 + g1;
        adj[e] = (j > i && y0 >= y1) ? 1.f : 0.f;
    }
}

// ============ K4: fused deg + agg + lin + BN partials (8-col tile) ============
__global__ __launch_bounds__(256) void k_gnn(
    const float* __restrict__ adj, const float* __restrict__ in,
    const float* __restrict__ scale_in, const float* __restrict__ shift_in, int aff,
    const float* __restrict__ wl, const float* __restrict__ bl,
    const float* __restrict__ wr,
    float* __restrict__ outb, float2* __restrict__ part2)
{
    int blk = blockIdx.x; int b = blk >> 4; int j0 = (blk & 15) * 8;
    int t = threadIdx.x; int h = t & 127; int g = t >> 7; int jg = j0 + 4*g;
    __shared__ __align__(16) float adjS[SS][8];
    __shared__ float4 red[2][64];
    __shared__ float4 aggL[2][HH], xnL[2][HH];

    for (int idx = t; idx < SS*8; idx += 256){
        int i = idx >> 3, jj = idx & 7;
        adjS[i][jj] = adj[(size_t)(b*SS+i)*SS + j0 + jj];
    }
    float sc = aff ? scale_in[h] : 1.f;
    float sh = aff ? shift_in[h] : 0.f;
    __syncthreads();
    if (h < 64)
        red[g][h] = f4add(*reinterpret_cast<float4*>(&adjS[h][4*g]),
                          *reinterpret_cast<float4*>(&adjS[h+64][4*g]));
    __syncthreads();
    for (int off = 32; off; off >>= 1){
        if (h < off) red[g][h] = f4add(red[g][h], red[g][h+off]);
        __syncthreads();
    }
    float4 ds = red[g][0];
    float4 dv = make_float4(1.f/fmaxf(ds.x,1.f), 1.f/fmaxf(ds.y,1.f),
                            1.f/fmaxf(ds.z,1.f), 1.f/fmaxf(ds.w,1.f));
    float a0=0.f, a1=0.f, a2=0.f, a3=0.f;
    const float* inb = in + (size_t)b*SS*HH + h;
    #pragma unroll 4
    for (int i = 0; i < SS; ++i){
        float xv = fmaf(inb[(size_t)i*HH], sc, sh);
        float4 av = *reinterpret_cast<float4*>(&adjS[i][4*g]);
        a0=fmaf(av.x,xv,a0); a1=fmaf(av.y,xv,a1);
        a2=fmaf(av.z,xv,a2); a3=fmaf(av.w,xv,a3);
    }
    aggL[g][h] = make_float4(a0*dv.x, a1*dv.y, a2*dv.z, a3*dv.w);
    size_t base = (size_t)(b*SS+jg)*HH + h;
    xnL[g][h] = make_float4(fmaf(in[base],sc,sh), fmaf(in[base+HH],sc,sh),
                            fmaf(in[base+2*HH],sc,sh), fmaf(in[base+3*HH],sc,sh));
    __syncthreads();
    float bv = bl[h];
    float acc[4] = {bv,bv,bv,bv};
    for (int c = 0; c < HH; ++c){
        float4 gg = aggL[g][c]; float4 xv = xnL[g][c];
        float wlv = wl[c*HH+h], wrv = wr[c*HH+h];
        acc[0]=fmaf(gg.x,wlv,acc[0]); acc[0]=fmaf(xv.x,wrv,acc[0]);
        acc[1]=fmaf(gg.y,wlv,acc[1]); acc[1]=fmaf(xv.y,wrv,acc[1]);
        acc[2]=fmaf(gg.z,wlv,acc[2]); acc[2]=fmaf(xv.z,wrv,acc[2]);
        acc[3]=fmaf(gg.w,wlv,acc[3]); acc[3]=fmaf(xv.w,wrv,acc[3]);
    }
    outb[base]      = acc[0];
    outb[base+HH]   = acc[1];
    outb[base+2*HH] = acc[2];
    outb[base+3*HH] = acc[3];
    float psum = acc[0]+acc[1]+acc[2]+acc[3];
    float psq  = acc[0]*acc[0]+acc[1]*acc[1]+acc[2]*acc[2]+acc[3]*acc[3];
    part2[(size_t)(blk*2+g)*HH + h] = make_float2(psum, psq);
}

// ============ K5: BN finalize + capture normalized last row ===================
__global__ __launch_bounds__(256) void k_bnfin(
    const float2* __restrict__ part2, const float* __restrict__ gamma,
    const float* __restrict__ beta, const float* __restrict__ outb,
    float* __restrict__ scale, float* __restrict__ shift, float* __restrict__ ol)
{
    int h = blockIdx.x; int t = threadIdx.x;
    float s1 = 0.f, s2 = 0.f;
    for (int i = t; i < 1024; i += 256){
        float2 v = part2[(size_t)i*HH + h];
        s1 += v.x; s2 += v.y;
    }
    __shared__ float r1[256], r2[256];
    __shared__ float sc_sh[2];
    r1[t] = s1; r2[t] = s2;
    __syncthreads();
    for (int off = 128; off; off >>= 1){
        if (t < off){ r1[t] += r1[t+off]; r2[t] += r2[t+off]; }
        __syncthreads();
    }
    if (t == 0){
        float m = r1[0] * (1.f/4096.f);
        float v = r2[0] * (1.f/4096.f) - m*m;
        v = fmaxf(v, 0.f);
        float sc = gamma[h] / sqrtf(v + 1e-5f);
        float sh = beta[h] - m*sc;
        scale[h] = sc; shift[h] = sh;
        sc_sh[0] = sc; sc_sh[1] = sh;
    }
    __syncthreads();
    if (t < BB){
        float val = outb[((size_t)t*SS + SS-1)*HH + h];
        ol[t*HH + h] = fmaf(val, sc_sh[0], sc_sh[1]);
    }
}

// ============ K6: head (gate -> we -> wo) =====================================
__global__ __launch_bounds__(128) void k_head(
    const float* __restrict__ ol, const float* __restrict__ wg,
    const float* __restrict__ bg, const float* __restrict__ we,
    const float* __restrict__ be, const float* __restrict__ wo,
    const float* __restrict__ bo, float* __restrict__ out)
{
    int b = blockIdx.x; int t = threadIdx.x;
    __shared__ float xw[HH];
    float a = bg[0];
    #pragma unroll
    for (int l = 0; l < 3; ++l) a = fmaf(ol[(l*BB + b)*HH + t], wg[l], a);
    xw[t] = fmaxf(a, 0.f);
    __syncthreads();
    if (t < 64){
        float acc = be[t];
        for (int h = 0; h < HH; ++h) acc = fmaf(xw[h], we[h*64 + t], acc);
        float h2 = fmaxf(acc, 0.f);
        float r = h2 * wo[t];
        #pragma unroll
        for (int off = 32; off; off >>= 1) r += __shfl_down(r, off, 64);
        if (t == 0) out[b] = r + bo[0];
    }
}

// ==============================================================================
extern "C" void kernel_launch(void* const* d_in, const int* in_sizes, int n_in,
                              void* d_out, int out_size, void* d_ws, size_t ws_size,
                              hipStream_t stream)
{
    const float* data = (const float*)d_in[0];
    const float* gu   = (const float*)d_in[1];
    const float* w11  = (const float*)d_in[2];
    const float* b11  = (const float*)d_in[3];
    const float* w12  = (const float*)d_in[4];
    const float* b12  = (const float*)d_in[5];
    const float* w21  = (const float*)d_in[6];
    const float* b21  = (const float*)d_in[7];
    const float* w22  = (const float*)d_in[8];
    const float* b22  = (const float*)d_in[9];
    const float* w31  = (const float*)d_in[10];
    const float* b31  = (const float*)d_in[11];
    const float* wf   = (const float*)d_in[12];
    const float* bf   = (const float*)d_in[13];
    const float* w1   = (const float*)d_in[14];
    const float* b1   = (const float*)d_in[15];
    const float* w2   = (const float*)d_in[16];
    const float* b2   = (const float*)d_in[17];
    const float* wl   = (const float*)d_in[18];
    const float* bl   = (const float*)d_in[19];
    const float* wr   = (const float*)d_in[20];
    const float* gamma= (const float*)d_in[21];
    const float* beta = (const float*)d_in[22];
    const float* wg   = (const float*)d_in[23];
    const float* bg   = (const float*)d_in[24];
    const float* we   = (const float*)d_in[25];
    const float* be   = (const float*)d_in[26];
    const float* wo   = (const float*)d_in[27];
    const float* bo   = (const float*)d_in[28];
    float* out = (float*)d_out;

    float* ws = (float*)d_ws;
    float* A  = ws;                        // x -> out L2
    float* Bq = ws + (size_t)NBSH;         // hsT -> out L0
    float* C  = ws + (size_t)2*NBSH;       // hr  -> out L1
    float* D  = ws + (size_t)3*NBSH;       // adj
    float2* part2 = (float2*)(ws + (size_t)4*NBSH);  // 1024*128 float2
    float* G = ws + (size_t)4*NBSH + 262144;
    float* W3    = G;                      // 48*128
    float* W5    = W3 + 48*HH;             // 80*128
    float* W31T  = W5 + 80*HH;             // 16*128
    float* Beff1 = W31T + 16*HH;           // 3*128
    float* Beff2 = Beff1 + 3*HH;           // 5*128
    float* scale = Beff2 + 5*HH;           // 3*128
    float* shift = scale + 3*HH;           // 3*128
    float* OL    = shift + 3*HH;           // 3*32*128
    float* w12T  = OL + 3*BB*HH;           // 384*128
    float* w22T  = w12T + 384*HH;          // 640*128
    float* xcatT = w22T + 640*HH;          // 384*4096 = 1.57M floats

    k_prep_t<<<130, 256, 0, stream>>>(w12, w22, w31, w12T, w22T, W31T);
    k_prep_w<<<136, 128, 0, stream>>>(w12T, w22T, w11, b11, w21, b21,
                                      W3, W5, Beff1, Beff2);
    k_conv_t<<<512, 256, 0, stream>>>(data, W3, W5, W31T, Beff1, Beff2,
                                      b12, b22, b31, xcatT);
    k_fuse_hs<<<512, 256, 0, stream>>>(xcatT, wf, bf, w1, b1, A, Bq, C);
    k_adj<<<512, 256, 0, stream>>>(Bq, C, w2, b2, gu, D);

    const float* inl[3] = {A, Bq, C};
    float* outl[3]      = {Bq, C, A};
    for (int l = 0; l < 3; ++l){
        int aff = (l > 0);
        const float* sc = scale + (l>0 ? (l-1)*HH : 0);
        const float* sh = shift + (l>0 ? (l-1)*HH : 0);
        k_gnn<<<512, 256, 0, stream>>>(D, inl[l], sc, sh, aff,
            wl + (size_t)l*HH*HH, bl + (size_t)l*HH, wr + (size_t)l*HH*HH,
            outl[l], part2);
        k_bnfin<<<HH, 256, 0, stream>>>(part2, gamma + (size_t)l*HH, beta + (size_t)l*HH,
            outl[l], scale + l*HH, shift + l*HH, OL + (size_t)l*BB*HH);
    }
    k_head<<<BB, 128, 0, stream>>>(OL, wg, bg, we, be, wo, bo, out);
}

// Round 7
// 188.988 us; speedup vs baseline: 1.0254x; 1.0254x over previous
//
#include <hip/hip_runtime.h>
#include <math.h>

#define BB 32
#define SS 128
#define DIN 16
#define HH 128
#define NROW (BB*SS)      // 4096
#define NBSH (BB*SS*HH)   // 524288

__device__ __forceinline__ float4 f4fma(float s, float4 w, float4 c){
    return make_float4(fmaf(s,w.x,c.x), fmaf(s,w.y,c.y), fmaf(s,w.z,c.z), fmaf(s,w.w,c.w));
}

// ============ K0a: coalesced-read transposes ==================================
__global__ __launch_bounds__(256) void k_prep_t(
    const float* __restrict__ w12, const float* __restrict__ w22,
    const float* __restrict__ w31,
    float* __restrict__ w12T, float* __restrict__ w22T, float* __restrict__ W31T)
{
    int idx4 = blockIdx.x*256 + threadIdx.x;   // 130*256 = 33280 exactly
    if (idx4 < 12288){
        float4 v = reinterpret_cast<const float4*>(w12)[idx4];
        int e = idx4*4; const float* pv = (const float*)&v;
        #pragma unroll
        for (int u = 0; u < 4; ++u){ int h=(e+u)/384, r=(e+u)%384; w12T[r*HH+h]=pv[u]; }
    } else if (idx4 < 32768){
        int q = idx4 - 12288;
        float4 v = reinterpret_cast<const float4*>(w22)[q];
        int e = q*4; const float* pv = (const float*)&v;
        #pragma unroll
        for (int u = 0; u < 4; ++u){ int h=(e+u)/640, r=(e+u)%640; w22T[r*HH+h]=pv[u]; }
    } else if (idx4 < 33280){
        int q = idx4 - 32768;
        float4 v = reinterpret_cast<const float4*>(w31)[q];
        int e = q*4; const float* pv = (const float*)&v;
        #pragma unroll
        for (int u = 0; u < 4; ++u){ int h=(e+u)/DIN, d=(e+u)%DIN; W31T[d*HH+h]=pv[u]; }
    }
}

// ============ K0b: composite conv weights (coalesced in h) ====================
__global__ __launch_bounds__(128) void k_prep_w(
    const float* __restrict__ w12T, const float* __restrict__ w22T,
    const float* __restrict__ w11, const float* __restrict__ b11,
    const float* __restrict__ w21, const float* __restrict__ b21,
    float* __restrict__ W3, float* __restrict__ W5,
    float* __restrict__ Beff1, float* __restrict__ Beff2)
{
    int blk = blockIdx.x; int h = threadIdx.x;
    if (blk < 48){
        int k = blk >> 4, d = blk & 15;
        float acc = 0.f;
        #pragma unroll 4
        for (int c = 0; c < HH; ++c)
            acc = fmaf(w12T[(c*3+k)*HH + h], w11[c*DIN + d], acc);
        W3[(k*DIN+d)*HH + h] = acc;
    } else if (blk < 128){
        int kk = blk - 48; int k = kk >> 4, d = kk & 15;
        float acc = 0.f;
        #pragma unroll 4
        for (int c = 0; c < HH; ++c)
            acc = fmaf(w22T[(c*5+k)*HH + h], w21[c*DIN + d], acc);
        W5[(k*DIN+d)*HH + h] = acc;
    } else {
        int j = blk - 128;   // 0..7
        if (j < 3){
            float a = 0.f;
            #pragma unroll 4
            for (int c = 0; c < HH; ++c) a = fmaf(w12T[(c*3+j)*HH + h], b11[c], a);
            Beff1[j*HH + h] = a;
        } else {
            int k = j - 3;
            float a = 0.f;
            #pragma unroll 4
            for (int c = 0; c < HH; ++c) a = fmaf(w22T[(c*5+k)*HH + h], b21[c], a);
            Beff2[k*HH + h] = a;
        }
    }
}

// ============ K1: conv front end -> xcat[row][384] ============================
__global__ __launch_bounds__(256) void k_conv(
    const float* __restrict__ data,
    const float* __restrict__ W3, const float* __restrict__ W5,
    const float* __restrict__ W31T,
    const float* __restrict__ Beff1, const float* __restrict__ Beff2,
    const float* __restrict__ b12, const float* __restrict__ b22,
    const float* __restrict__ b31,
    float* __restrict__ xcat)
{
    int blk = blockIdx.x; int b = blk >> 4; int s0 = (blk & 15) * 8;
    int t = threadIdx.x; int h = t & 127; int g = t >> 7; int tg = 4*g;
    __shared__ __align__(16) float dinT[DIN*28];   // [d][r], sp = s0-10+r

    for (int idx = t; idx < 28*DIN; idx += 256){
        int r = idx >> 4, d = idx & 15;
        int sp = s0 - 10 + r;
        dinT[d*28 + r] = (sp >= 0 && sp < SS) ? data[(b*SS+sp)*DIN + d] : 0.f;
    }
    __syncthreads();

    float acc1[4] = {0,0,0,0}, acc2[4] = {0,0,0,0}, acc3[4] = {0,0,0,0};
    for (int d = 0; d < DIN; ++d){
        const float4* qp = reinterpret_cast<const float4*>(dinT + d*28 + tg);
        float4 q0=qp[0], q1=qp[1], q2=qp[2], q3=qp[3], q4=qp[4], q5=qp[5];
        float qf[24] = {q0.x,q0.y,q0.z,q0.w, q1.x,q1.y,q1.z,q1.w,
                        q2.x,q2.y,q2.z,q2.w, q3.x,q3.y,q3.z,q3.w,
                        q4.x,q4.y,q4.z,q4.w, q5.x,q5.y,q5.z,q5.w};
        #pragma unroll
        for (int k = 0; k < 3; ++k){
            float w = W3[(k*DIN+d)*HH + h];
            #pragma unroll
            for (int tp = 0; tp < 4; ++tp)
                acc1[tp] = fmaf(qf[tp + 3*k + 7], w, acc1[tp]);
        }
        #pragma unroll
        for (int k = 0; k < 5; ++k){
            float w = W5[(k*DIN+d)*HH + h];
            #pragma unroll
            for (int tp = 0; tp < 4; ++tp)
                acc2[tp] = fmaf(qf[tp + 5*k], w, acc2[tp]);
        }
        float w31v = W31T[d*HH + h];
        #pragma unroll
        for (int tp = 0; tp < 4; ++tp)
            acc3[tp] = fmaf(qf[tp + 10], w31v, acc3[tp]);
    }
    float be1[3] = {Beff1[h], Beff1[HH+h], Beff1[2*HH+h]};
    float be2[5] = {Beff2[h], Beff2[HH+h], Beff2[2*HH+h], Beff2[3*HH+h], Beff2[4*HH+h]};
    float bv12 = b12[h], bv22 = b22[h], bv31 = b31[h];
    size_t rb = (size_t)(b*SS + s0 + tg);
    #pragma unroll
    for (int tp = 0; tp < 4; ++tp){
        int s = s0 + tg + tp;
        float a1 = acc1[tp] + bv12;
        #pragma unroll
        for (int k = 0; k < 3; ++k)
            if ((unsigned)(s + 3*k - 3) < SS) a1 += be1[k];
        float a2 = acc2[tp] + bv22;
        #pragma unroll
        for (int k = 0; k < 5; ++k)
            if ((unsigned)(s + 5*k - 10) < SS) a2 += be2[k];
        xcat[(rb+tp)*384 + h]       = a1;
        xcat[(rb+tp)*384 + 128 + h] = a2;
        xcat[(rb+tp)*384 + 256 + h] = acc3[tp] + bv31;
    }
}

// ============ K2: tiled fuse GEMM (K=384) + relu + hs/hr GEMM (K=128) =========
// block: 32 rows x 128 cols; 256 thr; 4x4 per thread.
__global__ __launch_bounds__(256) void k_fuse_hs(
    const float* __restrict__ xcat,
    const float* __restrict__ wf, const float* __restrict__ bf,
    const float* __restrict__ w1, const float* __restrict__ b1,
    float* __restrict__ x, float* __restrict__ hsT, float* __restrict__ hr)
{
    __shared__ __align__(16) float xT[128*36];   // x-tile transposed [c][row]
    __shared__ __align__(16) float sb[8192];     // phase1: At[32*36]+Wt[32*128]; phase2: Wa/Wb
    int blk = blockIdx.x; int row0 = blk*32;
    int tid = threadIdx.x;
    int r0 = (tid>>5)*4, c0 = (tid&31)*4;
    int srow = tid>>3, sk4 = (tid&7)*4;

    float4 acc[4] = {{0,0,0,0},{0,0,0,0},{0,0,0,0},{0,0,0,0}};
    float* At = sb;                 // [32][36]
    float* Wt = sb + 32*36;         // [32][128]
    for (int ch = 0; ch < 12; ++ch){
        int kk0 = ch*32;
        float4 av = *reinterpret_cast<const float4*>(xcat + (size_t)(row0+srow)*384 + kk0 + sk4);
        At[(sk4+0)*36 + srow] = av.x;
        At[(sk4+1)*36 + srow] = av.y;
        At[(sk4+2)*36 + srow] = av.z;
        At[(sk4+3)*36 + srow] = av.w;
        #pragma unroll
        for (int u = 0; u < 4; ++u){
            int k = (tid>>5) + 8*u;
            *reinterpret_cast<float4*>(Wt + k*128 + c0) =
                *reinterpret_cast<const float4*>(wf + (size_t)(kk0+k)*128 + c0);
        }
        __syncthreads();
        #pragma unroll 4
        for (int k = 0; k < 32; ++k){
            float4 a = *reinterpret_cast<const float4*>(At + k*36 + r0);
            float4 w = *reinterpret_cast<const float4*>(Wt + k*128 + c0);
            acc[0] = f4fma(a.x, w, acc[0]);
            acc[1] = f4fma(a.y, w, acc[1]);
            acc[2] = f4fma(a.z, w, acc[2]);
            acc[3] = f4fma(a.w, w, acc[3]);
        }
        __syncthreads();
    }
    float4 bf4 = *reinterpret_cast<const float4*>(bf + c0);
    #pragma unroll
    for (int u = 0; u < 4; ++u){
        float4 v = make_float4(fmaxf(acc[u].x+bf4.x,0.f), fmaxf(acc[u].y+bf4.y,0.f),
                               fmaxf(acc[u].z+bf4.z,0.f), fmaxf(acc[u].w+bf4.w,0.f));
        *reinterpret_cast<float4*>(x + (size_t)(row0+r0+u)*128 + c0) = v;
        xT[(c0+0)*36 + r0+u] = v.x;
        xT[(c0+1)*36 + r0+u] = v.y;
        xT[(c0+2)*36 + r0+u] = v.z;
        xT[(c0+3)*36 + r0+u] = v.w;
    }
    __syncthreads();

    // phase 2: hs = x@w1[:128], hr = x@w1[128:] + b1
    float4 as[4] = {{0,0,0,0},{0,0,0,0},{0,0,0,0},{0,0,0,0}};
    float4 ar[4] = {{0,0,0,0},{0,0,0,0},{0,0,0,0},{0,0,0,0}};
    float* Wa = sb; float* Wb = sb + 4096;
    for (int ch = 0; ch < 4; ++ch){
        int ck0 = ch*32;
        #pragma unroll
        for (int u = 0; u < 4; ++u){
            int k = (tid>>5) + 8*u;
            *reinterpret_cast<float4*>(Wa + k*128 + c0) =
                *reinterpret_cast<const float4*>(w1 + (size_t)(ck0+k)*128 + c0);
            *reinterpret_cast<float4*>(Wb + k*128 + c0) =
                *reinterpret_cast<const float4*>(w1 + (size_t)(128+ck0+k)*128 + c0);
        }
        __syncthreads();
        #pragma unroll 4
        for (int k = 0; k < 32; ++k){
            float4 a = *reinterpret_cast<const float4*>(xT + (ck0+k)*36 + r0);
            float4 wa = *reinterpret_cast<const float4*>(Wa + k*128 + c0);
            float4 wb = *reinterpret_cast<const float4*>(Wb + k*128 + c0);
            as[0]=f4fma(a.x,wa,as[0]); ar[0]=f4fma(a.x,wb,ar[0]);
            as[1]=f4fma(a.y,wa,as[1]); ar[1]=f4fma(a.y,wb,ar[1]);
            as[2]=f4fma(a.z,wa,as[2]); ar[2]=f4fma(a.z,wb,ar[2]);
            as[3]=f4fma(a.w,wa,as[3]); ar[3]=f4fma(a.w,wb,ar[3]);
        }
        __syncthreads();
    }
    float4 b14 = *reinterpret_cast<const float4*>(b1 + c0);
    int bb = row0 >> 7; int rin = (row0 & 127) + r0;
    #pragma unroll
    for (int u = 0; u < 4; ++u){
        *reinterpret_cast<float4*>(hr + (size_t)(row0+r0+u)*128 + c0) =
            make_float4(ar[u].x+b14.x, ar[u].y+b14.y, ar[u].z+b14.z, ar[u].w+b14.w);
        hsT[((size_t)bb*HH + c0+0)*SS + rin+u] = as[u].x;
        hsT[((size_t)bb*HH + c0+1)*SS + rin+u] = as[u].y;
        hsT[((size_t)bb*HH + c0+2)*SS + rin+u] = as[u].z;
        hsT[((size_t)bb*HH + c0+3)*SS + rin+u] = as[u].w;
    }
}

// ============ K3: edge logits + gumbel argmax -> adj (8-i tile) ===============
__global__ __launch_bounds__(256) void k_adj(
    const float* __restrict__ hsT, const float* __restrict__ hr,
    const float* __restrict__ w2, const float* __restrict__ b2,
    const float* __restrict__ gu, float* __restrict__ adj)
{
    int blk = blockIdx.x; int b = blk >> 4; int i0 = (blk & 15) * 8;
    int t = threadIdx.x; int j = t & 127; int g = t >> 7; int ig = i0 + 4*g;
    __shared__ float4 hrT[2][HH];
    __shared__ float w20L[HH], w21L[HH];
    hrT[g][j] = make_float4(hr[(size_t)(b*SS+ig+0)*HH + j],
                            hr[(size_t)(b*SS+ig+1)*HH + j],
                            hr[(size_t)(b*SS+ig+2)*HH + j],
                            hr[(size_t)(b*SS+ig+3)*HH + j]);
    if (g == 0){ w20L[j] = w2[j*2]; w21L[j] = w2[j*2+1]; }
    __syncthreads();
    const float* hsb = hsT + (size_t)b*HH*SS;
    float d0[4] = {0,0,0,0}, d1[4] = {0,0,0,0};
    #pragma unroll 2
    for (int h = 0; h < HH; ++h){
        float hsv = hsb[h*SS + j];
        float4 hv = hrT[g][h];
        float wa = w20L[h], wb = w21L[h];
        float r0 = fmaxf(hsv + hv.x, 0.f);
        float r1 = fmaxf(hsv + hv.y, 0.f);
        float r2 = fmaxf(hsv + hv.z, 0.f);
        float r3 = fmaxf(hsv + hv.w, 0.f);
        d0[0]=fmaf(r0,wa,d0[0]); d1[0]=fmaf(r0,wb,d1[0]);
        d0[1]=fmaf(r1,wa,d0[1]); d1[1]=fmaf(r1,wb,d1[1]);
        d0[2]=fmaf(r2,wa,d0[2]); d1[2]=fmaf(r2,wb,d1[2]);
        d0[3]=fmaf(r3,wa,d0[3]); d1[3]=fmaf(r3,wb,d1[3]);
    }
    float b20 = b2[0], b21 = b2[1];
    #pragma unroll
    for (int ii = 0; ii < 4; ++ii){
        int i = ig + ii;
        size_t e = (size_t)(b*SS+i)*SS + j;
        float2 uv = *reinterpret_cast<const float2*>(gu + e*2);
        float u0 = fminf(fmaxf(uv.x, 1e-6f), 0.999999f);
        float u1 = fminf(fmaxf(uv.y, 1e-6f), 0.999999f);
        float g0 = -logf(-logf(u0));
        float g1 = -logf(-logf(u1));
        float y0 = d0[ii] + b20 + g0;
        float y1 = d1[ii] + b21 + g1;
        adj[e] = (j > i && y0 >= y1) ? 1.f : 0.f;
    }
}

// ============ K4: agg = (adj^T @ in_eff)/deg — tiled GEMM + inline deg ========
// block: one b, 32 j x 128 h; K = i = 128 in 4 chunks.
__global__ __launch_bounds__(256) void k_agg(
    const float* __restrict__ adj, const float* __restrict__ in,
    const float* __restrict__ scale_in, const float* __restrict__ shift_in, int aff,
    float* __restrict__ agg)
{
    __shared__ __align__(16) float S[32*36];     // adj chunk [i][j-tile]
    __shared__ __align__(16) float Bt[32*128];   // in_eff chunk [i][h]
    int blk = blockIdx.x; int b = blk >> 2; int j0 = (blk & 3) * 32;
    int tid = threadIdx.x;
    int jr0 = (tid>>5)*4, h0 = (tid&31)*4;
    int si = tid>>3, sj4 = (tid&7)*4;

    float4 sc4 = make_float4(1,1,1,1), sh4 = make_float4(0,0,0,0);
    if (aff){
        sc4 = *reinterpret_cast<const float4*>(scale_in + h0);
        sh4 = *reinterpret_cast<const float4*>(shift_in + h0);
    }
    float4 acc[4] = {{0,0,0,0},{0,0,0,0},{0,0,0,0},{0,0,0,0}};
    float4 deg = make_float4(0,0,0,0);
    for (int ch = 0; ch < 4; ++ch){
        int ic0 = ch*32;
        *reinterpret_cast<float4*>(S + si*36 + sj4) =
            *reinterpret_cast<const float4*>(adj + (size_t)(b*SS + ic0 + si)*SS + j0 + sj4);
        #pragma unroll
        for (int u = 0; u < 4; ++u){
            int k = (tid>>5) + 8*u;
            float4 v = *reinterpret_cast<const float4*>(in + (size_t)(b*SS+ic0+k)*HH + h0);
            if (aff) v = make_float4(fmaf(v.x,sc4.x,sh4.x), fmaf(v.y,sc4.y,sh4.y),
                                     fmaf(v.z,sc4.z,sh4.z), fmaf(v.w,sc4.w,sh4.w));
            *reinterpret_cast<float4*>(Bt + k*128 + h0) = v;
        }
        __syncthreads();
        #pragma unroll 4
        for (int i = 0; i < 32; ++i){
            float4 a = *reinterpret_cast<const float4*>(S + i*36 + jr0);
            float4 bv = *reinterpret_cast<const float4*>(Bt + i*128 + h0);
            acc[0] = f4fma(a.x, bv, acc[0]);
            acc[1] = f4fma(a.y, bv, acc[1]);
            acc[2] = f4fma(a.z, bv, acc[2]);
            acc[3] = f4fma(a.w, bv, acc[3]);
            deg.x += a.x; deg.y += a.y; deg.z += a.z; deg.w += a.w;
        }
        __syncthreads();
    }
    float dv[4] = {1.f/fmaxf(deg.x,1.f), 1.f/fmaxf(deg.y,1.f),
                   1.f/fmaxf(deg.z,1.f), 1.f/fmaxf(deg.w,1.f)};
    #pragma unroll
    for (int u = 0; u < 4; ++u){
        *reinterpret_cast<float4*>(agg + (size_t)(b*SS + j0 + jr0 + u)*HH + h0) =
            make_float4(acc[u].x*dv[u], acc[u].y*dv[u], acc[u].z*dv[u], acc[u].w*dv[u]);
    }
}

// ============ K5: out = agg@wl + in_eff@wr + bl — tiled GEMM + BN partials ====
__global__ __launch_bounds__(256) void k_lin(
    const float* __restrict__ agg, const float* __restrict__ in,
    const float* __restrict__ scale_in, const float* __restrict__ shift_in, int aff,
    const float* __restrict__ wl, const float* __restrict__ bl,
    const float* __restrict__ wr,
    float* __restrict__ outb, float2* __restrict__ part2)
{
    __shared__ __align__(16) float At[32*36];
    __shared__ __align__(16) float Wt[32*128];
    __shared__ __align__(16) float2 red[8*128];
    int blk = blockIdx.x; int row0 = blk*32;
    int tid = threadIdx.x;
    int r0 = (tid>>5)*4, c0 = (tid&31)*4;
    int srow = tid>>3, sk4 = (tid&7)*4;

    float4 acc[4] = {{0,0,0,0},{0,0,0,0},{0,0,0,0},{0,0,0,0}};
    for (int ch = 0; ch < 8; ++ch){
        bool second = (ch >= 4);
        int ck0 = second ? (ch-4)*32 : ch*32;
        const float* Asrc = second ? in : agg;
        const float* Wsrc = second ? wr : wl;
        float4 av = *reinterpret_cast<const float4*>(Asrc + (size_t)(row0+srow)*HH + ck0 + sk4);
        if (second && aff){
            float4 s4 = *reinterpret_cast<const float4*>(scale_in + ck0 + sk4);
            float4 h4 = *reinterpret_cast<const float4*>(shift_in + ck0 + sk4);
            av = make_float4(fmaf(av.x,s4.x,h4.x), fmaf(av.y,s4.y,h4.y),
                             fmaf(av.z,s4.z,h4.z), fmaf(av.w,s4.w,h4.w));
        }
        At[(sk4+0)*36 + srow] = av.x;
        At[(sk4+1)*36 + srow] = av.y;
        At[(sk4+2)*36 + srow] = av.z;
        At[(sk4+3)*36 + srow] = av.w;
        #pragma unroll
        for (int u = 0; u < 4; ++u){
            int k = (tid>>5) + 8*u;
            *reinterpret_cast<float4*>(Wt + k*128 + c0) =
                *reinterpret_cast<const float4*>(Wsrc + (size_t)(ck0+k)*128 + c0);
        }
        __syncthreads();
        #pragma unroll 4
        for (int k = 0; k < 32; ++k){
            float4 a = *reinterpret_cast<const float4*>(At + k*36 + r0);
            float4 w = *reinterpret_cast<const float4*>(Wt + k*128 + c0);
            acc[0] = f4fma(a.x, w, acc[0]);
            acc[1] = f4fma(a.y, w, acc[1]);
            acc[2] = f4fma(a.z, w, acc[2]);
            acc[3] = f4fma(a.w, w, acc[3]);
        }
        __syncthreads();
    }
    float4 bl4 = *reinterpret_cast<const float4*>(bl + c0);
    float4 psum = make_float4(0,0,0,0), psq = make_float4(0,0,0,0);
    #pragma unroll
    for (int u = 0; u < 4; ++u){
        float4 v = make_float4(acc[u].x+bl4.x, acc[u].y+bl4.y, acc[u].z+bl4.z, acc[u].w+bl4.w);
        *reinterpret_cast<float4*>(outb + (size_t)(row0+r0+u)*128 + c0) = v;
        psum.x += v.x; psum.y += v.y; psum.z += v.z; psum.w += v.w;
        psq.x = fmaf(v.x,v.x,psq.x); psq.y = fmaf(v.y,v.y,psq.y);
        psq.z = fmaf(v.z,v.z,psq.z); psq.w = fmaf(v.w,v.w,psq.w);
    }
    int mg = tid>>5;
    red[mg*128 + c0+0] = make_float2(psum.x, psq.x);
    red[mg*128 + c0+1] = make_float2(psum.y, psq.y);
    red[mg*128 + c0+2] = make_float2(psum.z, psq.z);
    red[mg*128 + c0+3] = make_float2(psum.w, psq.w);
    __syncthreads();
    if (tid < 128){
        float s1 = 0.f, s2 = 0.f;
        #pragma unroll
        for (int m = 0; m < 8; ++m){
            float2 v = red[m*128 + tid];
            s1 += v.x; s2 += v.y;
        }
        part2[(size_t)tid*128 + blk] = make_float2(s1, s2);
    }
}

// ============ K6: BN finalize + capture normalized last row ===================
__global__ __launch_bounds__(128) void k_bnfin(
    const float2* __restrict__ part2, const float* __restrict__ gamma,
    const float* __restrict__ beta, const float* __restrict__ outb,
    float* __restrict__ scale, float* __restrict__ shift, float* __restrict__ ol)
{
    int h = blockIdx.x; int t = threadIdx.x;
    __shared__ float r1[128], r2[128];
    __shared__ float sc_sh[2];
    float2 v = part2[(size_t)h*128 + t];
    r1[t] = v.x; r2[t] = v.y;
    __syncthreads();
    for (int off = 64; off; off >>= 1){
        if (t < off){ r1[t] += r1[t+off]; r2[t] += r2[t+off]; }
        __syncthreads();
    }
    if (t == 0){
        float m = r1[0] * (1.f/4096.f);
        float var = r2[0] * (1.f/4096.f) - m*m;
        var = fmaxf(var, 0.f);
        float sc = gamma[h] / sqrtf(var + 1e-5f);
        float sh = beta[h] - m*sc;
        scale[h] = sc; shift[h] = sh;
        sc_sh[0] = sc; sc_sh[1] = sh;
    }
    __syncthreads();
    if (t < BB){
        float val = outb[((size_t)t*SS + SS-1)*HH + h];
        ol[t*HH + h] = fmaf(val, sc_sh[0], sc_sh[1]);
    }
}

// ============ K7: head (gate -> we -> wo) =====================================
__global__ __launch_bounds__(128) void k_head(
    const float* __restrict__ ol, const float* __restrict__ wg,
    const float* __restrict__ bg, const float* __restrict__ we,
    const float* __restrict__ be, const float* __restrict__ wo,
    const float* __restrict__ bo, float* __restrict__ out)
{
    int b = blockIdx.x; int t = threadIdx.x;
    __shared__ float xw[HH];
    float a = bg[0];
    #pragma unroll
    for (int l = 0; l < 3; ++l) a = fmaf(ol[(l*BB + b)*HH + t], wg[l], a);
    xw[t] = fmaxf(a, 0.f);
    __syncthreads();
    if (t < 64){
        float acc = be[t];
        for (int h = 0; h < HH; ++h) acc = fmaf(xw[h], we[h*64 + t], acc);
        float h2 = fmaxf(acc, 0.f);
        float r = h2 * wo[t];
        #pragma unroll
        for (int off = 32; off; off >>= 1) r += __shfl_down(r, off, 64);
        if (t == 0) out[b] = r + bo[0];
    }
}

// ==============================================================================
extern "C" void kernel_launch(void* const* d_in, const int* in_sizes, int n_in,
                              void* d_out, int out_size, void* d_ws, size_t ws_size,
                              hipStream_t stream)
{
    const float* data = (const float*)d_in[0];
    const float* gu   = (const float*)d_in[1];
    const float* w11  = (const float*)d_in[2];
    const float* b11  = (const float*)d_in[3];
    const float* w12  = (const float*)d_in[4];
    const float* b12  = (const float*)d_in[5];
    const float* w21  = (const float*)d_in[6];
    const float* b21  = (const float*)d_in[7];
    const float* w22  = (const float*)d_in[8];
    const float* b22  = (const float*)d_in[9];
    const float* w31  = (const float*)d_in[10];
    const float* b31  = (const float*)d_in[11];
    const float* wf   = (const float*)d_in[12];
    const float* bf   = (const float*)d_in[13];
    const float* w1   = (const float*)d_in[14];
    const float* b1   = (const float*)d_in[15];
    const float* w2   = (const float*)d_in[16];
    const float* b2   = (const float*)d_in[17];
    const float* wl   = (const float*)d_in[18];
    const float* bl   = (const float*)d_in[19];
    const float* wr   = (const float*)d_in[20];
    const float* gamma= (const float*)d_in[21];
    const float* beta = (const float*)d_in[22];
    const float* wg   = (const float*)d_in[23];
    const float* bg   = (const float*)d_in[24];
    const float* we   = (const float*)d_in[25];
    const float* be   = (const float*)d_in[26];
    const float* wo   = (const float*)d_in[27];
    const float* bo   = (const float*)d_in[28];
    float* out = (float*)d_out;

    float* ws = (float*)d_ws;
    float* A   = ws;                       // x; out L2
    float* Bq  = A + (size_t)NBSH;         // hsT; out L0
    float* C   = Bq + (size_t)NBSH;        // hr; out L1
    float* D   = C + (size_t)NBSH;         // adj
    float* E   = D + (size_t)NBSH;         // agg
    float2* part2 = (float2*)(E + (size_t)NBSH);     // 128*128 float2
    float* G = E + (size_t)NBSH + 32768;
    float* W3    = G;                      // 48*128
    float* W5    = W3 + 48*HH;             // 80*128
    float* W31T  = W5 + 80*HH;             // 16*128
    float* Beff1 = W31T + 16*HH;           // 3*128
    float* Beff2 = Beff1 + 3*HH;           // 5*128
    float* scale = Beff2 + 5*HH;           // 3*128
    float* shift = scale + 3*HH;           // 3*128
    float* OL    = shift + 3*HH;           // 3*32*128
    float* w12T  = OL + 3*BB*HH;           // 384*128
    float* w22T  = w12T + 384*HH;          // 640*128
    float* xcat  = w22T + 640*HH;          // 4096*384

    k_prep_t<<<130, 256, 0, stream>>>(w12, w22, w31, w12T, w22T, W31T);
    k_prep_w<<<136, 128, 0, stream>>>(w12T, w22T, w11, b11, w21, b21,
                                      W3, W5, Beff1, Beff2);
    k_conv<<<512, 256, 0, stream>>>(data, W3, W5, W31T, Beff1, Beff2,
                                    b12, b22, b31, xcat);
    k_fuse_hs<<<128, 256, 0, stream>>>(xcat, wf, bf, w1, b1, A, Bq, C);
    k_adj<<<512, 256, 0, stream>>>(Bq, C, w2, b2, gu, D);

    const float* inl[3] = {A, Bq, C};
    float* outl[3]      = {Bq, C, A};
    for (int l = 0; l < 3; ++l){
        int aff = (l > 0);
        const float* sc = scale + (l>0 ? (l-1)*HH : 0);
        const float* sh = shift + (l>0 ? (l-1)*HH : 0);
        k_agg<<<128, 256, 0, stream>>>(D, inl[l], sc, sh, aff, E);
        k_lin<<<128, 256, 0, stream>>>(E, inl[l], sc, sh, aff,
            wl + (size_t)l*HH*HH, bl + (size_t)l*HH, wr + (size_t)l*HH*HH,
            outl[l], part2);
        k_bnfin<<<HH, 128, 0, stream>>>(part2, gamma + (size_t)l*HH, beta + (size_t)l*HH,
            outl[l], scale + l*HH, shift + l*HH, OL + (size_t)l*BB*HH);
    }
    k_head<<<BB, 128, 0, stream>>>(OL, wg, bg, we, be, wo, bo, out);
}

// Round 8
// 178.514 us; speedup vs baseline: 1.0856x; 1.0587x over previous
//
#include <hip/hip_runtime.h>
#include <math.h>

#define BB 32
#define SS 128
#define DIN 16
#define HH 128
#define NROW (BB*SS)      // 4096
#define NBSH (BB*SS*HH)   // 524288

__device__ __forceinline__ float4 f4fma(float s, float4 w, float4 c){
    return make_float4(fmaf(s,w.x,c.x), fmaf(s,w.y,c.y), fmaf(s,w.z,c.z), fmaf(s,w.w,c.w));
}

// ============ K0: prep — composite conv weights + zero BN accumulators ========
// block g owns 8 h-channels; stages w12/w22 rows in LDS (coalesced), computes
// W3[(k*16+d)*128+h], W5, Beff1/2, W31T. Block 0 zeroes accf[768].
__global__ __launch_bounds__(256) void k_prep(
    const float* __restrict__ w12, const float* __restrict__ w22,
    const float* __restrict__ w31,
    const float* __restrict__ w11, const float* __restrict__ b11,
    const float* __restrict__ w21, const float* __restrict__ b21,
    float* __restrict__ W3, float* __restrict__ W5, float* __restrict__ W31T,
    float* __restrict__ Beff1, float* __restrict__ Beff2, float* __restrict__ accf)
{
    __shared__ float W12L[8*384];
    __shared__ float W22L[8*640];
    __shared__ float w11L[2048], w21L[2048], b11L[128], b21L[128];
    int g = blockIdx.x; int h0 = g*8; int tid = threadIdx.x;

    for (int i = tid; i < 768; i += 256){
        int hl = i/96, o4 = i%96;
        *reinterpret_cast<float4*>(W12L + hl*384 + o4*4) =
            reinterpret_cast<const float4*>(w12)[(h0+hl)*96 + o4];
    }
    for (int i = tid; i < 1280; i += 256){
        int hl = i/160, o4 = i%160;
        *reinterpret_cast<float4*>(W22L + hl*640 + o4*4) =
            reinterpret_cast<const float4*>(w22)[(h0+hl)*160 + o4];
    }
    for (int i = tid; i < 512; i += 256)
        *reinterpret_cast<float4*>(w11L + i*4) = reinterpret_cast<const float4*>(w11)[i];
    for (int i = tid; i < 512; i += 256)
        *reinterpret_cast<float4*>(w21L + i*4) = reinterpret_cast<const float4*>(w21)[i];
    if (tid < 128){ b11L[tid] = b11[tid]; b21L[tid] = b21[tid]; }
    if (g == 0){ for (int i = tid; i < 768; i += 256) accf[i] = 0.f; }
    __syncthreads();

    for (int T = tid; T < 1216; T += 256){
        if (T < 384){
            int hl = T/48, kd = T%48, k = kd>>4, d = kd&15;
            float a = 0.f;
            #pragma unroll 4
            for (int c = 0; c < HH; ++c) a = fmaf(W12L[hl*384 + c*3 + k], w11L[c*16 + d], a);
            W3[(k*16+d)*128 + h0+hl] = a;
        } else if (T < 1024){
            int tt = T-384, hl = tt/80, kd = tt%80, k = kd>>4, d = kd&15;
            float a = 0.f;
            #pragma unroll 4
            for (int c = 0; c < HH; ++c) a = fmaf(W22L[hl*640 + c*5 + k], w21L[c*16 + d], a);
            W5[(k*16+d)*128 + h0+hl] = a;
        } else if (T < 1048){
            int tt = T-1024, hl = tt/3, k = tt%3;
            float a = 0.f;
            #pragma unroll 4
            for (int c = 0; c < HH; ++c) a = fmaf(W12L[hl*384 + c*3 + k], b11L[c], a);
            Beff1[k*128 + h0+hl] = a;
        } else if (T < 1088){
            int tt = T-1048, hl = tt/5, k = tt%5;
            float a = 0.f;
            #pragma unroll 4
            for (int c = 0; c < HH; ++c) a = fmaf(W22L[hl*640 + c*5 + k], b21L[c], a);
            Beff2[k*128 + h0+hl] = a;
        } else {
            int tt = T-1088, hl = tt>>4, d = tt&15;
            W31T[d*128 + h0+hl] = w31[(h0+hl)*16 + d];
        }
    }
}

// ============ K1: conv -> (LDS) -> fuse GEMM -> relu -> hs/hr GEMMs ===========
// 128 blocks x 256 thr; block owns 32 rows of one batch b.
__global__ __launch_bounds__(256) void k_fuse_all(
    const float* __restrict__ data,
    const float* __restrict__ W3, const float* __restrict__ W5,
    const float* __restrict__ W31T,
    const float* __restrict__ Beff1, const float* __restrict__ Beff2,
    const float* __restrict__ b12, const float* __restrict__ b22,
    const float* __restrict__ b31,
    const float* __restrict__ wf, const float* __restrict__ bf,
    const float* __restrict__ w1, const float* __restrict__ b1,
    float* __restrict__ x, float* __restrict__ hsT, float* __restrict__ hr)
{
    __shared__ __align__(16) float sb[18752];   // 75 KB
    float* At   = sb;            // phase1: conv out [384][36]; phase2: xT[128][36] @0, Wb @4608
    float* Wt   = sb + 13824;    // [32][128] weight chunk (phase2: Wa)
    float* dinT = sb + 17920;    // [16][52]
    int blk = blockIdx.x; int row0 = blk*32;
    int b = row0 >> 7; int s0 = row0 & 127;
    int tid = threadIdx.x; int h = tid & 127; int g = tid >> 7;

    for (int idx = tid; idx < 832; idx += 256){
        int r = idx >> 4, d = idx & 15;
        int sp = s0 - 10 + r;
        dinT[d*52 + r] = (sp >= 0 && sp < SS) ? data[(b*SS+sp)*DIN + d] : 0.f;
    }
    __syncthreads();

    // ---- conv: this thread computes channel h for 16 rows (g*4 within each 8) ----
    float a1[16], a2[16], a3[16];
    #pragma unroll
    for (int m = 0; m < 16; ++m){ a1[m]=0.f; a2[m]=0.f; a3[m]=0.f; }
    for (int d = 0; d < DIN; ++d){
        float w3v[3], w5v[5];
        #pragma unroll
        for (int k = 0; k < 3; ++k) w3v[k] = W3[(k*DIN+d)*HH + h];
        #pragma unroll
        for (int k = 0; k < 5; ++k) w5v[k] = W5[(k*DIN+d)*HH + h];
        float w31v = W31T[d*HH + h];
        const float* dp = dinT + d*52;
        #pragma unroll
        for (int sub = 0; sub < 4; ++sub){
            int rb = sub*8 + g*4;
            const float4* qp = reinterpret_cast<const float4*>(dp + rb);
            float4 q0=qp[0],q1=qp[1],q2=qp[2],q3=qp[3],q4=qp[4],q5=qp[5];
            float qf[24] = {q0.x,q0.y,q0.z,q0.w, q1.x,q1.y,q1.z,q1.w,
                            q2.x,q2.y,q2.z,q2.w, q3.x,q3.y,q3.z,q3.w,
                            q4.x,q4.y,q4.z,q4.w, q5.x,q5.y,q5.z,q5.w};
            #pragma unroll
            for (int tp = 0; tp < 4; ++tp){
                int m = sub*4 + tp;
                #pragma unroll
                for (int k = 0; k < 3; ++k) a1[m] = fmaf(qf[tp+3*k+7], w3v[k], a1[m]);
                #pragma unroll
                for (int k = 0; k < 5; ++k) a2[m] = fmaf(qf[tp+5*k], w5v[k], a2[m]);
                a3[m] = fmaf(qf[tp+10], w31v, a3[m]);
            }
        }
    }
    {
        float be1[3] = {Beff1[h], Beff1[HH+h], Beff1[2*HH+h]};
        float be2[5] = {Beff2[h], Beff2[HH+h], Beff2[2*HH+h], Beff2[3*HH+h], Beff2[4*HH+h]};
        float bv12 = b12[h], bv22 = b22[h], bv31 = b31[h];
        #pragma unroll
        for (int m = 0; m < 16; ++m){
            int sub = m >> 2, tp = m & 3;
            int rl = sub*8 + g*4 + tp;       // local row 0..31
            int s = s0 + rl;
            float v1 = a1[m] + bv12;
            #pragma unroll
            for (int k = 0; k < 3; ++k)
                if ((unsigned)(s + 3*k - 3) < SS) v1 += be1[k];
            float v2 = a2[m] + bv22;
            #pragma unroll
            for (int k = 0; k < 5; ++k)
                if ((unsigned)(s + 5*k - 10) < SS) v2 += be2[k];
            At[h*36 + rl]         = v1;
            At[(HH+h)*36 + rl]    = v2;
            At[(2*HH+h)*36 + rl]  = a3[m] + bv31;
        }
    }
    __syncthreads();

    // ---- fuse GEMM: x = relu(xcat @ wf + bf), A resident in LDS ----
    int r0 = (tid>>5)*4, c0 = (tid&31)*4;
    float4 facc[4] = {{0,0,0,0},{0,0,0,0},{0,0,0,0},{0,0,0,0}};
    for (int ch = 0; ch < 12; ++ch){
        int kk0 = ch*32;
        #pragma unroll
        for (int u = 0; u < 4; ++u){
            int k = (tid>>5) + 8*u;
            *reinterpret_cast<float4*>(Wt + k*128 + c0) =
                *reinterpret_cast<const float4*>(wf + (size_t)(kk0+k)*128 + c0);
        }
        __syncthreads();
        #pragma unroll 4
        for (int k = 0; k < 32; ++k){
            float4 a = *reinterpret_cast<const float4*>(At + (kk0+k)*36 + r0);
            float4 w = *reinterpret_cast<const float4*>(Wt + k*128 + c0);
            facc[0] = f4fma(a.x, w, facc[0]);
            facc[1] = f4fma(a.y, w, facc[1]);
            facc[2] = f4fma(a.z, w, facc[2]);
            facc[3] = f4fma(a.w, w, facc[3]);
        }
        __syncthreads();
    }
    float* xT = sb;            // reuse At region (all reads done)
    float* Wa = sb + 13824;
    float* Wb = sb + 4608;
    {
        float4 bf4 = *reinterpret_cast<const float4*>(bf + c0);
        #pragma unroll
        for (int u = 0; u < 4; ++u){
            float4 v = make_float4(fmaxf(facc[u].x+bf4.x,0.f), fmaxf(facc[u].y+bf4.y,0.f),
                                   fmaxf(facc[u].z+bf4.z,0.f), fmaxf(facc[u].w+bf4.w,0.f));
            *reinterpret_cast<float4*>(x + (size_t)(row0+r0+u)*128 + c0) = v;
            xT[(c0+0)*36 + r0+u] = v.x;
            xT[(c0+1)*36 + r0+u] = v.y;
            xT[(c0+2)*36 + r0+u] = v.z;
            xT[(c0+3)*36 + r0+u] = v.w;
        }
    }
    __syncthreads();

    // ---- hs/hr GEMMs (K=128) ----
    float4 as[4] = {{0,0,0,0},{0,0,0,0},{0,0,0,0},{0,0,0,0}};
    float4 ar[4] = {{0,0,0,0},{0,0,0,0},{0,0,0,0},{0,0,0,0}};
    for (int ch = 0; ch < 4; ++ch){
        int ck0 = ch*32;
        #pragma unroll
        for (int u = 0; u < 4; ++u){
            int k = (tid>>5) + 8*u;
            *reinterpret_cast<float4*>(Wa + k*128 + c0) =
                *reinterpret_cast<const float4*>(w1 + (size_t)(ck0+k)*128 + c0);
            *reinterpret_cast<float4*>(Wb + k*128 + c0) =
                *reinterpret_cast<const float4*>(w1 + (size_t)(128+ck0+k)*128 + c0);
        }
        __syncthreads();
        #pragma unroll 4
        for (int k = 0; k < 32; ++k){
            float4 a = *reinterpret_cast<const float4*>(xT + (ck0+k)*36 + r0);
            float4 wa = *reinterpret_cast<const float4*>(Wa + k*128 + c0);
            float4 wb = *reinterpret_cast<const float4*>(Wb + k*128 + c0);
            as[0]=f4fma(a.x,wa,as[0]); ar[0]=f4fma(a.x,wb,ar[0]);
            as[1]=f4fma(a.y,wa,as[1]); ar[1]=f4fma(a.y,wb,ar[1]);
            as[2]=f4fma(a.z,wa,as[2]); ar[2]=f4fma(a.z,wb,ar[2]);
            as[3]=f4fma(a.w,wa,as[3]); ar[3]=f4fma(a.w,wb,ar[3]);
        }
        __syncthreads();
    }
    float4 b14 = *reinterpret_cast<const float4*>(b1 + c0);
    int bb = row0 >> 7; int rin = (row0 & 127) + r0;
    #pragma unroll
    for (int u = 0; u < 4; ++u){
        *reinterpret_cast<float4*>(hr + (size_t)(row0+r0+u)*128 + c0) =
            make_float4(ar[u].x+b14.x, ar[u].y+b14.y, ar[u].z+b14.z, ar[u].w+b14.w);
        hsT[((size_t)bb*HH + c0+0)*SS + rin+u] = as[u].x;
        hsT[((size_t)bb*HH + c0+1)*SS + rin+u] = as[u].y;
        hsT[((size_t)bb*HH + c0+2)*SS + rin+u] = as[u].z;
        hsT[((size_t)bb*HH + c0+3)*SS + rin+u] = as[u].w;
    }
}

// ============ K2: edge logits + gumbel argmax -> adj (8-i tile) ===============
__global__ __launch_bounds__(256) void k_adj(
    const float* __restrict__ hsT, const float* __restrict__ hr,
    const float* __restrict__ w2, const float* __restrict__ b2,
    const float* __restrict__ gu, float* __restrict__ adj)
{
    int blk = blockIdx.x; int b = blk >> 4; int i0 = (blk & 15) * 8;
    int t = threadIdx.x; int j = t & 127; int g = t >> 7; int ig = i0 + 4*g;
    __shared__ float4 hrT[2][HH];
    __shared__ float w20L[HH], w21L[HH];
    hrT[g][j] = make_float4(hr[(size_t)(b*SS+ig+0)*HH + j],
                            hr[(size_t)(b*SS+ig+1)*HH + j],
                            hr[(size_t)(b*SS+ig+2)*HH + j],
                            hr[(size_t)(b*SS+ig+3)*HH + j]);
    if (g == 0){ w20L[j] = w2[j*2]; w21L[j] = w2[j*2+1]; }
    __syncthreads();
    const float* hsb = hsT + (size_t)b*HH*SS;
    float d0[4] = {0,0,0,0}, d1[4] = {0,0,0,0};
    #pragma unroll 2
    for (int h = 0; h < HH; ++h){
        float hsv = hsb[h*SS + j];
        float4 hv = hrT[g][h];
        float wa = w20L[h], wb = w21L[h];
        float r0 = fmaxf(hsv + hv.x, 0.f);
        float r1 = fmaxf(hsv + hv.y, 0.f);
        float r2 = fmaxf(hsv + hv.z, 0.f);
        float r3 = fmaxf(hsv + hv.w, 0.f);
        d0[0]=fmaf(r0,wa,d0[0]); d1[0]=fmaf(r0,wb,d1[0]);
        d0[1]=fmaf(r1,wa,d0[1]); d1[1]=fmaf(r1,wb,d1[1]);
        d0[2]=fmaf(r2,wa,d0[2]); d1[2]=fmaf(r2,wb,d1[2]);
        d0[3]=fmaf(r3,wa,d0[3]); d1[3]=fmaf(r3,wb,d1[3]);
    }
    float b20 = b2[0], b21 = b2[1];
    #pragma unroll
    for (int ii = 0; ii < 4; ++ii){
        int i = ig + ii;
        size_t e = (size_t)(b*SS+i)*SS + j;
        float2 uv = *reinterpret_cast<const float2*>(gu + e*2);
        float u0 = fminf(fmaxf(uv.x, 1e-6f), 0.999999f);
        float u1 = fminf(fmaxf(uv.y, 1e-6f), 0.999999f);
        float g0 = -logf(-logf(u0));
        float g1 = -logf(-logf(u1));
        float y0 = d0[ii] + b20 + g0;
        float y1 = d1[ii] + b21 + g1;
        adj[e] = (j > i && y0 >= y1) ? 1.f : 0.f;
    }
}

// ============ K3: fused agg (adj^T @ in_eff / deg) + lin GEMM + BN atomics ====
// 128 blocks x 256 thr; block = (b, 32-j tile). Input BN applied via accP sums.
__global__ __launch_bounds__(256) void k_gnn(
    const float* __restrict__ adj, const float* __restrict__ in,
    const float* __restrict__ gammaP, const float* __restrict__ betaP,
    const float* __restrict__ accP, int aff,
    const float* __restrict__ wl, const float* __restrict__ bl,
    const float* __restrict__ wr,
    float* __restrict__ outb, float* __restrict__ accL)
{
    __shared__ __align__(16) float S[32*36];
    __shared__ __align__(16) float Bt[32*128];
    __shared__ __align__(16) float At[128*36];
    __shared__ __align__(16) float Wt[32*128];
    __shared__ float2 scsh[128];
    __shared__ float2 red[8*128];
    int blk = blockIdx.x; int b = blk >> 2; int j0 = (blk & 3) * 32;
    int row0 = b*SS + j0;
    int tid = threadIdx.x;
    int jr0 = (tid>>5)*4, h0 = (tid&31)*4;
    int si = tid>>3, sj4 = (tid&7)*4;

    if (tid < 128){
        if (aff){
            float2 s = reinterpret_cast<const float2*>(accP)[tid];
            float m = s.x * (1.f/4096.f);
            float var = fmaxf(s.y * (1.f/4096.f) - m*m, 0.f);
            float sc = gammaP[tid] / sqrtf(var + 1e-5f);
            scsh[tid] = make_float2(sc, betaP[tid] - m*sc);
        } else {
            scsh[tid] = make_float2(1.f, 0.f);
        }
    }
    __syncthreads();
    float2 ss0 = scsh[h0+0], ss1 = scsh[h0+1], ss2 = scsh[h0+2], ss3 = scsh[h0+3];

    // ---- agg phase ----
    float4 acc[4] = {{0,0,0,0},{0,0,0,0},{0,0,0,0},{0,0,0,0}};
    float4 deg = make_float4(0,0,0,0);
    for (int ch = 0; ch < 4; ++ch){
        int ic0 = ch*32;
        *reinterpret_cast<float4*>(S + si*36 + sj4) =
            *reinterpret_cast<const float4*>(adj + (size_t)(b*SS+ic0+si)*SS + j0 + sj4);
        #pragma unroll
        for (int u = 0; u < 4; ++u){
            int k = (tid>>5) + 8*u;
            float4 v = *reinterpret_cast<const float4*>(in + (size_t)(b*SS+ic0+k)*HH + h0);
            v = make_float4(fmaf(v.x,ss0.x,ss0.y), fmaf(v.y,ss1.x,ss1.y),
                            fmaf(v.z,ss2.x,ss2.y), fmaf(v.w,ss3.x,ss3.y));
            *reinterpret_cast<float4*>(Bt + k*128 + h0) = v;
        }
        __syncthreads();
        #pragma unroll 4
        for (int i = 0; i < 32; ++i){
            float4 a = *reinterpret_cast<const float4*>(S + i*36 + jr0);
            float4 bv = *reinterpret_cast<const float4*>(Bt + i*128 + h0);
            acc[0] = f4fma(a.x, bv, acc[0]);
            acc[1] = f4fma(a.y, bv, acc[1]);
            acc[2] = f4fma(a.z, bv, acc[2]);
            acc[3] = f4fma(a.w, bv, acc[3]);
            deg.x += a.x; deg.y += a.y; deg.z += a.z; deg.w += a.w;
        }
        __syncthreads();
    }
    float dv[4] = {1.f/fmaxf(deg.x,1.f), 1.f/fmaxf(deg.y,1.f),
                   1.f/fmaxf(deg.z,1.f), 1.f/fmaxf(deg.w,1.f)};
    #pragma unroll
    for (int ju = 0; ju < 4; ++ju){
        At[(h0+0)*36 + jr0+ju] = acc[ju].x * dv[ju];
        At[(h0+1)*36 + jr0+ju] = acc[ju].y * dv[ju];
        At[(h0+2)*36 + jr0+ju] = acc[ju].z * dv[ju];
        At[(h0+3)*36 + jr0+ju] = acc[ju].w * dv[ju];
    }

    // ---- lin: agg @ wl ----
    float4 oacc[4] = {{0,0,0,0},{0,0,0,0},{0,0,0,0},{0,0,0,0}};
    for (int ch = 0; ch < 4; ++ch){
        int ck0 = ch*32;
        #pragma unroll
        for (int u = 0; u < 4; ++u){
            int k = (tid>>5) + 8*u;
            *reinterpret_cast<float4*>(Wt + k*128 + h0) =
                *reinterpret_cast<const float4*>(wl + (size_t)(ck0+k)*HH + h0);
        }
        __syncthreads();
        #pragma unroll 4
        for (int k = 0; k < 32; ++k){
            float4 a = *reinterpret_cast<const float4*>(At + (ck0+k)*36 + jr0);
            float4 w = *reinterpret_cast<const float4*>(Wt + k*128 + h0);
            oacc[0] = f4fma(a.x, w, oacc[0]);
            oacc[1] = f4fma(a.y, w, oacc[1]);
            oacc[2] = f4fma(a.z, w, oacc[2]);
            oacc[3] = f4fma(a.w, w, oacc[3]);
        }
        __syncthreads();
    }
    // ---- lin: in_eff @ wr (A chunk staged into S) ----
    for (int ch = 0; ch < 4; ++ch){
        int ck0 = ch*32;
        {
            float4 av = *reinterpret_cast<const float4*>(in + (size_t)(row0+si)*HH + ck0 + sj4);
            float2 t0 = scsh[ck0+sj4+0], t1 = scsh[ck0+sj4+1];
            float2 t2 = scsh[ck0+sj4+2], t3 = scsh[ck0+sj4+3];
            S[(sj4+0)*36 + si] = fmaf(av.x, t0.x, t0.y);
            S[(sj4+1)*36 + si] = fmaf(av.y, t1.x, t1.y);
            S[(sj4+2)*36 + si] = fmaf(av.z, t2.x, t2.y);
            S[(sj4+3)*36 + si] = fmaf(av.w, t3.x, t3.y);
        }
        #pragma unroll
        for (int u = 0; u < 4; ++u){
            int k = (tid>>5) + 8*u;
            *reinterpret_cast<float4*>(Wt + k*128 + h0) =
                *reinterpret_cast<const float4*>(wr + (size_t)(ck0+k)*HH + h0);
        }
        __syncthreads();
        #pragma unroll 4
        for (int k = 0; k < 32; ++k){
            float4 a = *reinterpret_cast<const float4*>(S + k*36 + jr0);
            float4 w = *reinterpret_cast<const float4*>(Wt + k*128 + h0);
            oacc[0] = f4fma(a.x, w, oacc[0]);
            oacc[1] = f4fma(a.y, w, oacc[1]);
            oacc[2] = f4fma(a.z, w, oacc[2]);
            oacc[3] = f4fma(a.w, w, oacc[3]);
        }
        __syncthreads();
    }
    // ---- bias, store, BN partials + atomics ----
    float4 bl4 = *reinterpret_cast<const float4*>(bl + h0);
    float4 psum = make_float4(0,0,0,0), psq = make_float4(0,0,0,0);
    #pragma unroll
    for (int u = 0; u < 4; ++u){
        float4 v = make_float4(oacc[u].x+bl4.x, oacc[u].y+bl4.y,
                               oacc[u].z+bl4.z, oacc[u].w+bl4.w);
        *reinterpret_cast<float4*>(outb + (size_t)(row0+jr0+u)*HH + h0) = v;
        psum.x += v.x; psum.y += v.y; psum.z += v.z; psum.w += v.w;
        psq.x = fmaf(v.x,v.x,psq.x); psq.y = fmaf(v.y,v.y,psq.y);
        psq.z = fmaf(v.z,v.z,psq.z); psq.w = fmaf(v.w,v.w,psq.w);
    }
    int mg = tid>>5;
    red[mg*128 + h0+0] = make_float2(psum.x, psq.x);
    red[mg*128 + h0+1] = make_float2(psum.y, psq.y);
    red[mg*128 + h0+2] = make_float2(psum.z, psq.z);
    red[mg*128 + h0+3] = make_float2(psum.w, psq.w);
    __syncthreads();
    if (tid < 128){
        float s1 = 0.f, s2 = 0.f;
        #pragma unroll
        for (int m = 0; m < 8; ++m){
            float2 v = red[m*128 + tid];
            s1 += v.x; s2 += v.y;
        }
        atomicAdd(&accL[2*tid],   s1);
        atomicAdd(&accL[2*tid+1], s2);
    }
}

// ============ K4: head — final BN on lastrows + gate + MLP ====================
__global__ __launch_bounds__(128) void k_head(
    const float* __restrict__ o0, const float* __restrict__ o1,
    const float* __restrict__ o2, const float* __restrict__ accf,
    const float* __restrict__ gamma, const float* __restrict__ beta,
    const float* __restrict__ wg, const float* __restrict__ bg,
    const float* __restrict__ we, const float* __restrict__ be,
    const float* __restrict__ wo, const float* __restrict__ bo,
    float* __restrict__ out)
{
    int b = blockIdx.x; int t = threadIdx.x;
    __shared__ float xw[HH];
    const float* outs[3] = {o0, o1, o2};
    float a = bg[0];
    #pragma unroll
    for (int l = 0; l < 3; ++l){
        float2 s = reinterpret_cast<const float2*>(accf)[l*128 + t];
        float m = s.x * (1.f/4096.f);
        float var = fmaxf(s.y * (1.f/4096.f) - m*m, 0.f);
        float sc = gamma[l*128+t] / sqrtf(var + 1e-5f);
        float sh = beta[l*128+t] - m*sc;
        float val = fmaf(outs[l][((size_t)b*SS + SS-1)*HH + t], sc, sh);
        a = fmaf(val, wg[l], a);
    }
    xw[t] = fmaxf(a, 0.f);
    __syncthreads();
    if (t < 64){
        float acc = be[t];
        for (int h = 0; h < HH; ++h) acc = fmaf(xw[h], we[h*64 + t], acc);
        float h2 = fmaxf(acc, 0.f);
        float r = h2 * wo[t];
        #pragma unroll
        for (int off = 32; off; off >>= 1) r += __shfl_down(r, off, 64);
        if (t == 0) out[b] = r + bo[0];
    }
}

// ==============================================================================
extern "C" void kernel_launch(void* const* d_in, const int* in_sizes, int n_in,
                              void* d_out, int out_size, void* d_ws, size_t ws_size,
                              hipStream_t stream)
{
    const float* data = (const float*)d_in[0];
    const float* gu   = (const float*)d_in[1];
    const float* w11  = (const float*)d_in[2];
    const float* b11  = (const float*)d_in[3];
    const float* w12  = (const float*)d_in[4];
    const float* b12  = (const float*)d_in[5];
    const float* w21  = (const float*)d_in[6];
    const float* b21  = (const float*)d_in[7];
    const float* w22  = (const float*)d_in[8];
    const float* b22  = (const float*)d_in[9];
    const float* w31  = (const float*)d_in[10];
    const float* b31  = (const float*)d_in[11];
    const float* wf   = (const float*)d_in[12];
    const float* bf   = (const float*)d_in[13];
    const float* w1   = (const float*)d_in[14];
    const float* b1   = (const float*)d_in[15];
    const float* w2   = (const float*)d_in[16];
    const float* b2   = (const float*)d_in[17];
    const float* wl   = (const float*)d_in[18];
    const float* bl   = (const float*)d_in[19];
    const float* wr   = (const float*)d_in[20];
    const float* gamma= (const float*)d_in[21];
    const float* beta = (const float*)d_in[22];
    const float* wg   = (const float*)d_in[23];
    const float* bg   = (const float*)d_in[24];
    const float* we   = (const float*)d_in[25];
    const float* be   = (const float*)d_in[26];
    const float* wo   = (const float*)d_in[27];
    const float* bo   = (const float*)d_in[28];
    float* out = (float*)d_out;

    float* ws = (float*)d_ws;
    float* A  = ws;                        // x; out L2
    float* Bq = A + (size_t)NBSH;          // hsT; out L0
    float* C  = Bq + (size_t)NBSH;         // hr; out L1
    float* D  = C + (size_t)NBSH;          // adj
    float* G  = D + (size_t)NBSH;
    float* W3    = G;                      // 48*128  = 6144
    float* W5    = W3 + 6144;              // 80*128  = 10240
    float* W31T  = W5 + 10240;             // 16*128  = 2048
    float* Beff1 = W31T + 2048;            // 384
    float* Beff2 = Beff1 + 384;            // 640
    float* accf  = Beff2 + 640;            // 3*128*2 = 768 (8B-aligned offset)

    k_prep<<<16, 256, 0, stream>>>(w12, w22, w31, w11, b11, w21, b21,
                                   W3, W5, W31T, Beff1, Beff2, accf);
    k_fuse_all<<<128, 256, 0, stream>>>(data, W3, W5, W31T, Beff1, Beff2,
                                        b12, b22, b31, wf, bf, w1, b1,
                                        A, Bq, C);
    k_adj<<<512, 256, 0, stream>>>(Bq, C, w2, b2, gu, D);

    const float* inl[3]  = {A, Bq, C};
    float*       outl[3] = {Bq, C, A};
    for (int l = 0; l < 3; ++l){
        int aff = (l > 0);
        const float* gP = gamma + (l>0 ? (l-1)*HH : 0);
        const float* bP = beta  + (l>0 ? (l-1)*HH : 0);
        const float* aP = accf + (l>0 ? (l-1)*256 : 0);
        k_gnn<<<128, 256, 0, stream>>>(D, inl[l], gP, bP, aP, aff,
            wl + (size_t)l*HH*HH, bl + (size_t)l*HH, wr + (size_t)l*HH*HH,
            outl[l], accf + (size_t)l*256);
    }
    k_head<<<BB, 128, 0, stream>>>(Bq, C, A, accf, gamma, beta,
                                   wg, bg, we, be, wo, bo, out);
}